// Round 1
// baseline (3727.017 us; speedup 1.0000x reference)
//
#include <hip/hip_runtime.h>
#include <cstdint>
#include <cstddef>

#define HDIM 128
#define GBM 64
#define GBK 32

__device__ __forceinline__ float sigmoidf_(float x) {
  return 1.0f / (1.0f + __expf(-x));
}

// ---------------- generic f32 GEMM: C[M,128] (+)= A[M,K] @ W[K,128] (+bias)(+relu)
// blockIdx.z batches over weight/output slabs (strideWz/strideCz in elements).
__global__ __launch_bounds__(256) void gemm128_f32(
    const float* __restrict__ A, const float* __restrict__ Wg,
    const float* __restrict__ bias, float* __restrict__ C,
    int M, int K, int accumulate, int post,
    long long strideWz, long long strideCz)
{
  __shared__ float As[GBM][GBK + 1];
  __shared__ float Ws[GBK][HDIM + 4];
  const float* Wp = Wg + (long long)blockIdx.z * strideWz;
  float* Cp = C + (long long)blockIdx.z * strideCz;
  const int m0 = blockIdx.x * GBM;
  const int tid = threadIdx.x;
  const int tx = tid & 15;   // col group: cols tx*8 .. tx*8+7
  const int ty = tid >> 4;   // row group: rows ty*4 .. ty*4+3

  float acc[4][8];
#pragma unroll
  for (int i = 0; i < 4; ++i)
#pragma unroll
    for (int j = 0; j < 8; ++j) acc[i][j] = 0.f;

  const int lar = tid >> 2;          // A-tile row this thread stages
  const int lac = (tid & 3) * 8;     // A-tile col base (8 floats)
  const int lwk = tid >> 3;          // W-tile row
  const int lwj = (tid & 7) * 16;    // W-tile col base (16 floats)

  for (int k0 = 0; k0 < K; k0 += GBK) {
    float4 v0 = make_float4(0.f, 0.f, 0.f, 0.f), v1 = v0;
    {
      int gr = m0 + lar;
      if (gr < M) {
        const float* src = A + (long long)gr * K + (k0 + lac);
        v0 = *(const float4*)(src);
        v1 = *(const float4*)(src + 4);
      }
    }
    const float* wsrc = Wp + (long long)(k0 + lwk) * HDIM + lwj;
    float4 w0 = *(const float4*)(wsrc);
    float4 w1 = *(const float4*)(wsrc + 4);
    float4 w2 = *(const float4*)(wsrc + 8);
    float4 w3 = *(const float4*)(wsrc + 12);

    As[lar][lac + 0] = v0.x; As[lar][lac + 1] = v0.y;
    As[lar][lac + 2] = v0.z; As[lar][lac + 3] = v0.w;
    As[lar][lac + 4] = v1.x; As[lar][lac + 5] = v1.y;
    As[lar][lac + 6] = v1.z; As[lar][lac + 7] = v1.w;
    {
      float* wd = &Ws[lwk][lwj];
      wd[0]  = w0.x; wd[1]  = w0.y; wd[2]  = w0.z; wd[3]  = w0.w;
      wd[4]  = w1.x; wd[5]  = w1.y; wd[6]  = w1.z; wd[7]  = w1.w;
      wd[8]  = w2.x; wd[9]  = w2.y; wd[10] = w2.z; wd[11] = w2.w;
      wd[12] = w3.x; wd[13] = w3.y; wd[14] = w3.z; wd[15] = w3.w;
    }
    __syncthreads();

#pragma unroll 8
    for (int kk = 0; kk < GBK; ++kk) {
      float a0 = As[ty * 4 + 0][kk];
      float a1 = As[ty * 4 + 1][kk];
      float a2 = As[ty * 4 + 2][kk];
      float a3 = As[ty * 4 + 3][kk];
      float4 wa = *(const float4*)&Ws[kk][tx * 8];
      float4 wb = *(const float4*)&Ws[kk][tx * 8 + 4];
      float w[8] = {wa.x, wa.y, wa.z, wa.w, wb.x, wb.y, wb.z, wb.w};
#pragma unroll
      for (int j = 0; j < 8; ++j) {
        acc[0][j] += a0 * w[j];
        acc[1][j] += a1 * w[j];
        acc[2][j] += a2 * w[j];
        acc[3][j] += a3 * w[j];
      }
    }
    __syncthreads();
  }

#pragma unroll
  for (int i = 0; i < 4; ++i) {
    int gr = m0 + ty * 4 + i;
    if (gr >= M) continue;
    float* crow = Cp + (long long)gr * HDIM + tx * 8;
    float v[8];
#pragma unroll
    for (int j = 0; j < 8; ++j) v[j] = acc[i][j];
    if (bias) {
#pragma unroll
      for (int j = 0; j < 8; ++j) v[j] += bias[tx * 8 + j];
    }
    if (accumulate) {
      float4 c0 = *(const float4*)crow;
      float4 c1 = *(const float4*)(crow + 4);
      v[0] += c0.x; v[1] += c0.y; v[2] += c0.z; v[3] += c0.w;
      v[4] += c1.x; v[5] += c1.y; v[6] += c1.z; v[7] += c1.w;
    }
    if (post == 1) {
#pragma unroll
      for (int j = 0; j < 8; ++j) v[j] = fmaxf(v[j], 0.f);
    }
    *(float4*)crow = make_float4(v[0], v[1], v[2], v[3]);
    *(float4*)(crow + 4) = make_float4(v[4], v[5], v[6], v[7]);
  }
}

// ---------------- elementwise kernels ----------------
__global__ __launch_bounds__(256) void k_dnode(
    float* __restrict__ h, float* __restrict__ pc,
    const int* __restrict__ batch, const int* __restrict__ dom_ids,
    const float* __restrict__ dom_emb, int ntot)
{
  int idx = blockIdx.x * 256 + threadIdx.x;
  if (idx >= ntot) return;
  int n = idx >> 7, j = idx & 127;
  float d = dom_emb[dom_ids[batch[n]] * HDIM + j];
  h[idx] *= d;
  pc[idx] *= d;
}

__global__ __launch_bounds__(256) void k_combine(
    float* __restrict__ h, const float* __restrict__ pc,
    const float* __restrict__ pglin, const float* __restrict__ pa, int ntot)
{
  int idx = blockIdx.x * 256 + threadIdx.x;
  if (idx >= ntot) return;
  float pg = sigmoidf_(pglin[idx]);
  h[idx] = pg * h[idx] + (1.f - pg) * pc[idx] + pa[idx];
}

__global__ __launch_bounds__(256) void k_add(
    const float* __restrict__ a, const float* __restrict__ b,
    float* __restrict__ c, int ntot)
{
  int idx = blockIdx.x * 256 + threadIdx.x;
  if (idx >= ntot) return;
  c[idx] = a[idx] + b[idx];
}

__global__ __launch_bounds__(256) void k_out(
    const float* __restrict__ fglin, const float* __restrict__ sem,
    const float* __restrict__ stru, float* __restrict__ out, int ntot)
{
  int idx = blockIdx.x * 256 + threadIdx.x;
  if (idx >= ntot) return;
  float fg = sigmoidf_(fglin[idx]);
  out[idx] = fg * sem[idx] + (1.f - fg) * stru[idx];
}

// ---------------- graph kernels ----------------
__global__ __launch_bounds__(256) void k_edgecount(
    const int* __restrict__ ei, const int* __restrict__ etype,
    const int* __restrict__ epid, int* __restrict__ cntp,
    int* __restrict__ cnt8, int E)
{
  int e = blockIdx.x * 256 + threadIdx.x;
  if (e >= E) return;
  int s = ei[e];
  int d = ei[E + e];
  int et = etype[e];
  int p = epid[e];
  p = p < 0 ? 0 : (p > 15 ? 15 : p);
  atomicAdd(&cntp[s * 16 + p], 1);
  atomicAdd(&cnt8[d * 8 + et], 1);
}

__global__ __launch_bounds__(256) void k_propagg(
    const int* __restrict__ cntp, const float* __restrict__ pemb,
    float* __restrict__ pa, int ntot)
{
  int idx = blockIdx.x * 256 + threadIdx.x;
  if (idx >= ntot) return;
  int n = idx >> 7, j = idx & 127;
  int deg = 0;
  float acc = 0.f;
#pragma unroll
  for (int p = 0; p < 16; ++p) {
    int c = cntp[n * 16 + p];
    deg += c;
    acc += (float)c * pemb[p * HDIM + j];
  }
  pa[idx] = acc / (float)(deg > 1 ? deg : 1);
}

__global__ __launch_bounds__(256) void k_invcnt(
    const int* __restrict__ cnt8, float* __restrict__ invc, int ntot)
{
  int idx = blockIdx.x * 256 + threadIdx.x;
  if (idx >= ntot) return;
  int c = cnt8[idx];
  invc[idx] = 1.f / (float)(c > 1 ? c : 1);
}

// conv[dst] += Y[et][src] * inv_cnt[dst,et]  for edges with et in [r0, r0+rc)
__global__ __launch_bounds__(256) void k_scatter(
    const int* __restrict__ ei, const int* __restrict__ etype,
    const float* __restrict__ invc, const float* __restrict__ Y,
    float* __restrict__ conv, int E, int NN, int r0, int rc)
{
  int t = blockIdx.x * 256 + threadIdx.x;
  int e = t >> 7;
  int j = t & 127;
  if (e >= E) return;
  int et = etype[e];
  if (et < r0 || et >= r0 + rc) return;
  int s = ei[e];
  int d = ei[E + e];
  float w = invc[d * 8 + et];
  float v = Y[((long long)(et - r0) * NN + s) * HDIM + j] * w;
  atomicAdd(&conv[(long long)d * HDIM + j], v);
}

// curr_out = relu(conv + 2.0 * (x @ la) @ lb), 16 nodes per block
__global__ __launch_bounds__(256) void k_lora_relu(
    const float* __restrict__ xin, const float* __restrict__ conv,
    const float* __restrict__ la, const float* __restrict__ lb,
    float* __restrict__ outc, int NN)
{
  __shared__ float xs[16][129];
  __shared__ float las[128 * 8];
  __shared__ float lbs[8 * 128];
  __shared__ float Tsh[16][9];
  int tid = threadIdx.x;
  int n0 = blockIdx.x * 16;

  for (int i = tid; i < 1024; i += 256) {
    las[i] = la[i];
    lbs[i] = lb[i];
  }
  for (int i = tid; i < 16 * 128; i += 256) {
    int nn = i >> 7, j = i & 127;
    int g = n0 + nn;
    xs[nn][j] = (g < NN) ? xin[(long long)g * HDIM + j] : 0.f;
  }
  __syncthreads();

  if (tid < 128) {
    int nn = tid >> 3, r = tid & 7;
    float s = 0.f;
#pragma unroll 16
    for (int k = 0; k < 128; ++k) s += xs[nn][k] * las[k * 8 + r];
    Tsh[nn][r] = s;
  }
  __syncthreads();

  int nn = tid >> 4;
  int j0 = (tid & 15) * 8;
  int g = n0 + nn;
  if (g < NN) {
    const float* cv = conv + (long long)g * HDIM + j0;
    float* op = outc + (long long)g * HDIM + j0;
    float o[8];
#pragma unroll
    for (int jj = 0; jj < 8; ++jj) {
      float s = 0.f;
#pragma unroll
      for (int r = 0; r < 8; ++r) s += Tsh[nn][r] * lbs[r * HDIM + j0 + jj];
      float v = cv[jj] + 2.0f * s;   // SCALING = 16/8 = 2
      o[jj] = fmaxf(v, 0.f);
    }
    *(float4*)op = make_float4(o[0], o[1], o[2], o[3]);
    *(float4*)(op + 4) = make_float4(o[4], o[5], o[6], o[7]);
  }
}

// ---------------- host ----------------
extern "C" void kernel_launch(void* const* d_in, const int* in_sizes, int n_in,
                              void* d_out, int out_size, void* d_ws, size_t ws_size,
                              hipStream_t stream)
{
  const int N = 100000, E = 800000, TEXT = 768, H = 128, R = 8, L = 2;
  const int NTOT = N * H;

  const float* x_text  = (const float*)d_in[0];
  const float* x_path  = (const float*)d_in[1];
  const float* text_w  = (const float*)d_in[2];
  const float* text_b  = (const float*)d_in[3];
  const float* path_w  = (const float*)d_in[4];
  const float* path_b  = (const float*)d_in[5];
  const float* dom_emb = (const float*)d_in[6];
  const float* prop_emb= (const float*)d_in[7];
  const float* pf_w    = (const float*)d_in[8];
  const float* pf_b    = (const float*)d_in[9];
  const float* pg1_w   = (const float*)d_in[10];
  const float* pg1_b   = (const float*)d_in[11];
  const float* pg2_w   = (const float*)d_in[12];
  const float* pg2_b   = (const float*)d_in[13];
  const float* sem_w   = (const float*)d_in[14];
  const float* sem_b   = (const float*)d_in[15];
  const float* str_w   = (const float*)d_in[16];
  const float* str_b   = (const float*)d_in[17];
  const float* g1_w    = (const float*)d_in[18];
  const float* g1_b    = (const float*)d_in[19];
  const float* g2_w    = (const float*)d_in[20];
  const float* g2_b    = (const float*)d_in[21];
  const float* rel_w   = (const float*)d_in[22];
  const float* root_w  = (const float*)d_in[23];
  const float* rbias   = (const float*)d_in[24];
  const float* lora_a  = (const float*)d_in[25];
  const float* lora_b  = (const float*)d_in[26];
  const int*   ei      = (const int*)d_in[27];
  const int*   etype   = (const int*)d_in[28];
  const int*   batch   = (const int*)d_in[29];
  const int*   dom_ids = (const int*)d_in[30];
  const int*   epid    = (const int*)d_in[31];
  float* out = (float*)d_out;

  const size_t NB = (size_t)NTOT * sizeof(float);   // 51.2 MB
  char* p = (char*)d_ws;
  auto alloc = [&](size_t bytes) -> void* {
    char* q = p;
    p += (bytes + 255) & ~(size_t)255;
    return (void*)q;
  };
  float* hbuf  = (float*)alloc(NB);
  float* pabuf = (float*)alloc(NB);
  float* curr  = (float*)alloc(NB);
  float* cin   = (float*)alloc(NB);
  float* conv  = (float*)alloc(NB);
  float* tmp   = (float*)alloc(NB);
  int*   cntp  = (int*)alloc((size_t)N * 16 * 4);
  int*   cnt8  = (int*)alloc((size_t)N * 8 * 4);
  float* invc  = (float*)alloc((size_t)N * 8 * 4);
  size_t used = (size_t)(p - (char*)d_ws);

  // relation-chunk size adapts to available workspace; fallback reuses `tmp`
  // (free during the RGCN layers) so the minimum footprint is ~320 MB.
  float* ybuf = tmp;
  int RC = 1;
  if (ws_size > used) {
    size_t k = (ws_size - used) / NB;
    if (k >= 1) {
      RC = (int)(k < 8 ? k : 8);
      ybuf = (float*)alloc(NB * (size_t)RC);
    }
  }

  const int GM = (N + GBM - 1) / GBM;
  const int EWG = (NTOT + 255) / 256;

  auto gemm = [&](const float* A, const float* W, const float* b, float* C,
                  int K, int accv, int post, int zc,
                  long long swz, long long scz) {
    gemm128_f32<<<dim3(GM, 1, zc), dim3(256), 0, stream>>>(
        A, W, b, C, N, K, accv, post, swz, scz);
  };

  // --- property / degree counting (independent of dense front-end) ---
  hipMemsetAsync(cntp, 0, (size_t)N * 24 * 4, stream);  // cntp + cnt8 contiguous
  k_edgecount<<<(E + 255) / 256, 256, 0, stream>>>(ei, etype, epid, cntp, cnt8, E);
  k_propagg<<<EWG, 256, 0, stream>>>(cntp, prop_emb, pabuf, NTOT);
  k_invcnt<<<(N * 8 + 255) / 256, 256, 0, stream>>>(cnt8, invc, N * 8);

  // --- front-end: projections, domain modulation, path gate ---
  gemm(x_text, text_w, text_b, hbuf, TEXT, 0, 0, 1, 0, 0);
  gemm(x_path, path_w, path_b, curr, TEXT, 0, 0, 1, 0, 0);
  k_dnode<<<EWG, 256, 0, stream>>>(hbuf, curr, batch, dom_ids, dom_emb, NTOT);
  gemm(curr, pf_w, pf_b, cin, H, 0, 0, 1, 0, 0);                 // path_ctx
  gemm(hbuf, pg1_w, pg1_b, conv, H, 0, 0, 1, 0, 0);              // h part
  gemm(cin, pg1_w + H * H, nullptr, conv, H, 1, 1, 1, 0, 0);     // + pc part, relu
  gemm(conv, pg2_w, pg2_b, tmp, H, 0, 0, 1, 0, 0);               // pgate linear
  k_combine<<<EWG, 256, 0, stream>>>(hbuf, cin, tmp, pabuf, NTOT);

  // --- RGCN layers ---
  for (int l = 0; l < L; ++l) {
    const float* src = (l == 0) ? hbuf : curr;
    k_add<<<EWG, 256, 0, stream>>>(src, pabuf, cin, NTOT);       // curr_in
    gemm(cin, root_w + (size_t)l * H * H, rbias + (size_t)l * H,
         conv, H, 0, 0, 1, 0, 0);                                 // root + bias
    for (int r0 = 0; r0 < R; r0 += RC) {
      int rc = (R - r0) < RC ? (R - r0) : RC;
      gemm(cin, rel_w + ((size_t)l * R + r0) * H * H, nullptr, ybuf,
           H, 0, 0, rc, (long long)H * H, (long long)NTOT);       // Y_r
      k_scatter<<<(E * 128 + 255) / 256, 256, 0, stream>>>(
          ei, etype, invc, ybuf, conv, E, N, r0, rc);
    }
    k_lora_relu<<<(N + 15) / 16, 256, 0, stream>>>(
        cin, conv, lora_a + (size_t)l * H * 8, lora_b + (size_t)l * 8 * H,
        curr, N);
  }

  // --- final gated fusion ---
  gemm(hbuf, sem_w, sem_b, conv, H, 0, 0, 1, 0, 0);              // sem
  gemm(curr, str_w, str_b, cin, H, 0, 0, 1, 0, 0);               // stru
  gemm(conv, g1_w, g1_b, tmp, H, 0, 0, 1, 0, 0);
  gemm(cin, g1_w + H * H, nullptr, tmp, H, 1, 1, 1, 0, 0);       // relu
  gemm(tmp, g2_w, g2_b, pabuf, H, 0, 0, 1, 0, 0);                // fg linear
  k_out<<<EWG, 256, 0, stream>>>(pabuf, conv, cin, out, NTOT);
}